// Round 1
// baseline (318.418 us; speedup 1.0000x reference)
//
#include <hip/hip_runtime.h>

#define B_    4
#define N_    11
#define D_    589824L     // 64*96*96
#define NP2   66          // upper-tri incl. diagonal, 11*12/2
#define NP1   55          // strict upper-tri (e1 diagonal is identically 0)
#define NRED  121         // NP2 + NP1
#define TPB   256
#define ITER  3           // floats per block = TPB*4*ITER = 3072; 589824/3072 = 192 blocks/batch
                          // -> grid 192*4 = 768 blocks = exactly 3 blocks/CU (matches VGPR residency cap)

// ---------------------------------------------------------------------------
// Canonical GCN wave64 sum-reduction via DPP (pure VALU, no LDS pipe).
// Result valid in lane 63. update_dpp(old=0,...): masked/invalid lanes add 0.
// ---------------------------------------------------------------------------
__device__ __forceinline__ float wave_red_add(float x) {
    int t;
    t = __builtin_amdgcn_update_dpp(0, __float_as_int(x), 0x111, 0xf, 0xf, false); x += __int_as_float(t); // row_shr:1
    t = __builtin_amdgcn_update_dpp(0, __float_as_int(x), 0x112, 0xf, 0xf, false); x += __int_as_float(t); // row_shr:2
    t = __builtin_amdgcn_update_dpp(0, __float_as_int(x), 0x114, 0xf, 0xf, false); x += __int_as_float(t); // row_shr:4
    t = __builtin_amdgcn_update_dpp(0, __float_as_int(x), 0x118, 0xf, 0xf, false); x += __int_as_float(t); // row_shr:8
    t = __builtin_amdgcn_update_dpp(0, __float_as_int(x), 0x142, 0xa, 0xf, false); x += __int_as_float(t); // row_bcast:15
    t = __builtin_amdgcn_update_dpp(0, __float_as_int(x), 0x143, 0xc, 0xf, false); x += __int_as_float(t); // row_bcast:31
    return x;
}

// ---------------------------------------------------------------------------
// Pass 1: pairwise reductions. e2[p] = <q_i,q_j> (66 pairs incl diag),
// e1[p] = sum|q_i-q_j| (55 strict pairs), fp64 atomics per batch.
// ---------------------------------------------------------------------------
__global__ __launch_bounds__(TPB, 3) void reduce_kernel(const float* __restrict__ x,
                                                        double* __restrict__ e2ws,
                                                        double* __restrict__ e1ws) {
    const int b = blockIdx.y;
    const int t = threadIdx.x;
    const long base = (long)blockIdx.x * (TPB * 4 * ITER) + (long)t * 4;
    const float* xb = x + (long)b * N_ * D_;

    float acc2[NP2];
    float acc1[NP1];
#pragma unroll
    for (int p = 0; p < NP2; ++p) acc2[p] = 0.f;
#pragma unroll
    for (int p = 0; p < NP1; ++p) acc1[p] = 0.f;

#pragma unroll 1
    for (int k = 0; k < ITER; ++k) {
        const long d = base + (long)k * (TPB * 4);
        float4 v[N_];
#pragma unroll
        for (int m = 0; m < N_; ++m)
            v[m] = *reinterpret_cast<const float4*>(xb + (long)m * D_ + d);

        int p2 = 0, p1 = 0;
#pragma unroll
        for (int i = 0; i < N_; ++i) {
#pragma unroll
            for (int j = i; j < N_; ++j) {
                acc2[p2] += v[i].x * v[j].x + v[i].y * v[j].y +
                            v[i].z * v[j].z + v[i].w * v[j].w;
                ++p2;
                if (j > i) {
                    acc1[p1] += fabsf(v[i].x - v[j].x) + fabsf(v[i].y - v[j].y) +
                                fabsf(v[i].z - v[j].z) + fabsf(v[i].w - v[j].w);
                    ++p1;
                }
            }
        }
    }

    // per-wave DPP reduce (VALU only), then cross-wave via tiny LDS table
    __shared__ float red[TPB / 64][NRED];
    const int wave = t >> 6, lane = t & 63;
#pragma unroll
    for (int p = 0; p < NP2; ++p) {
        const float s = wave_red_add(acc2[p]);
        if (lane == 63) red[wave][p] = s;
    }
#pragma unroll
    for (int p = 0; p < NP1; ++p) {
        const float s = wave_red_add(acc1[p]);
        if (lane == 63) red[wave][NP2 + p] = s;
    }
    __syncthreads();
    if (t < NRED) {
        float s = 0.f;
#pragma unroll
        for (int w = 0; w < TPB / 64; ++w) s += red[w][t];
        if (t < NP2) atomicAdd(&e2ws[b * NP2 + t], (double)s);
        else         atomicAdd(&e1ws[b * NP1 + (t - NP2)], (double)s);
    }
}

// ---------------------------------------------------------------------------
// Pass 2: energy = e1*e2 (symmetric, diag = 0); attention = softmax(-energy)
// per row; M[n,m] = gamma*attention[n,m] + (n==m).
// ---------------------------------------------------------------------------
__global__ __launch_bounds__(128) void attn_kernel(const double* __restrict__ e2ws,
                                                   const double* __restrict__ e1ws,
                                                   const float* __restrict__ gamma,
                                                   float* __restrict__ Mws) {
    const int b = blockIdx.x;
    const int t = threadIdx.x;
    __shared__ double E[N_][N_];
    if (t < NP2) {
        // decode upper-tri index t -> (i, j), i <= j
        int rem = t, i = 0, cnt = N_;
        while (rem >= cnt) { rem -= cnt; --cnt; ++i; }
        const int j = i + rem;
        double e = 0.0;
        if (j > i) {
            const int q = i * (2 * N_ - 1 - i) / 2 + (j - i - 1);  // strict-tri index
            e = e1ws[b * NP1 + q] * e2ws[b * NP2 + t];
        }
        E[i][j] = e;
        E[j][i] = e;
    }
    __syncthreads();
    if (t < N_) {
        const int i = t;
        double mn = E[i][0];
#pragma unroll
        for (int j = 1; j < N_; ++j) mn = fmin(mn, E[i][j]);
        double ex[N_], s = 0.0;
#pragma unroll
        for (int j = 0; j < N_; ++j) { ex[j] = exp(mn - E[i][j]); s += ex[j]; }
        const float g = gamma[0];
        const double inv = 1.0 / s;
#pragma unroll
        for (int j = 0; j < N_; ++j) {
            float m = (float)(ex[j] * inv) * g + (i == j ? 1.0f : 0.0f);
            Mws[(b * N_ + i) * N_ + j] = m;
        }
    }
}

// ---------------------------------------------------------------------------
// Pass 3: out[b,n,d] = sum_m M[b][n][m] * x[b,m,d]  (gamma & +x folded into M).
// Nontemporal stores: out is write-once, keep x resident in L3 instead.
// ---------------------------------------------------------------------------
typedef float nfloat4 __attribute__((ext_vector_type(4)));

__global__ __launch_bounds__(TPB) void apply_kernel(const float* __restrict__ x,
                                                    const float* __restrict__ Mws,
                                                    float* __restrict__ out) {
    const int b = blockIdx.y;
    const int t = threadIdx.x;
    __shared__ float M[N_ * N_];
    if (t < N_ * N_) M[t] = Mws[b * N_ * N_ + t];
    __syncthreads();

    const long d = (long)blockIdx.x * (TPB * 4) + (long)t * 4;
    const float* xb = x + (long)b * N_ * D_;
    float* ob = out + (long)b * N_ * D_;

    float4 v[N_];
#pragma unroll
    for (int m = 0; m < N_; ++m)
        v[m] = *reinterpret_cast<const float4*>(xb + (long)m * D_ + d);

#pragma unroll
    for (int n = 0; n < N_; ++n) {
        float4 o = make_float4(0.f, 0.f, 0.f, 0.f);
#pragma unroll
        for (int m = 0; m < N_; ++m) {
            const float w = M[n * N_ + m];
            o.x += w * v[m].x;
            o.y += w * v[m].y;
            o.z += w * v[m].z;
            o.w += w * v[m].w;
        }
        union { float4 f; nfloat4 n4; } u;
        u.f = o;
        __builtin_nontemporal_store(u.n4, reinterpret_cast<nfloat4*>(ob + (long)n * D_ + d));
    }
}

// ---------------------------------------------------------------------------
extern "C" void kernel_launch(void* const* d_in, const int* in_sizes, int n_in,
                              void* d_out, int out_size, void* d_ws, size_t ws_size,
                              hipStream_t stream) {
    const float* x     = (const float*)d_in[0];
    const float* gamma = (const float*)d_in[1];
    float* out         = (float*)d_out;

    double* e2ws = (double*)d_ws;            // B_*NP2 doubles
    double* e1ws = e2ws + B_ * NP2;          // B_*NP1 doubles
    float*  Mws  = (float*)(e1ws + B_ * NP1);

    // zero the fp64 accumulators (ws is poisoned before every launch)
    hipMemsetAsync(d_ws, 0, (size_t)(B_ * (NP2 + NP1)) * sizeof(double), stream);

    dim3 gridA(D_ / (TPB * 4 * ITER), B_);   // (192, 4) = 768 blocks = 3/CU
    reduce_kernel<<<gridA, TPB, 0, stream>>>(x, e2ws, e1ws);

    attn_kernel<<<B_, 128, 0, stream>>>(e2ws, e1ws, gamma, Mws);

    dim3 gridC(D_ / (TPB * 4), B_);          // (576, 4)
    apply_kernel<<<gridC, TPB, 0, stream>>>(x, Mws, out);
}

// Round 2
// 218.253 us; speedup vs baseline: 1.4589x; 1.4589x over previous
//
#include <hip/hip_runtime.h>
#include <hip/hip_cooperative_groups.h>

namespace cg = cooperative_groups;

#define B_      4
#define N_      11
#define D_      589824L       // 64*96*96
#define NP2     66            // upper-tri incl diagonal
#define NP1     55            // strict upper-tri (e1 diag == 0)
#define TPB     256
#define CHUNKS  192           // blocks per batch -> grid 768 = exactly 3 blocks/CU
#define CFL     3072L         // floats per chunk = D_/CHUNKS
#define K1      6             // phase1: 128 lanes * 4 floats * 6 = 3072
#define K3      3             // phase3: 256 lanes * 4 floats * 3 = 3072

typedef float nfloat4 __attribute__((ext_vector_type(4)));

// ---------------------------------------------------------------------------
// wave64 sum-reduction via DPP (pure VALU). Result valid in lane 63.
// ---------------------------------------------------------------------------
__device__ __forceinline__ float wave_red_add(float x) {
    int t;
    t = __builtin_amdgcn_update_dpp(0, __float_as_int(x), 0x111, 0xf, 0xf, false); x += __int_as_float(t); // row_shr:1
    t = __builtin_amdgcn_update_dpp(0, __float_as_int(x), 0x112, 0xf, 0xf, false); x += __int_as_float(t); // row_shr:2
    t = __builtin_amdgcn_update_dpp(0, __float_as_int(x), 0x114, 0xf, 0xf, false); x += __int_as_float(t); // row_shr:4
    t = __builtin_amdgcn_update_dpp(0, __float_as_int(x), 0x118, 0xf, 0xf, false); x += __int_as_float(t); // row_shr:8
    t = __builtin_amdgcn_update_dpp(0, __float_as_int(x), 0x142, 0xa, 0xf, false); x += __int_as_float(t); // row_bcast:15
    t = __builtin_amdgcn_update_dpp(0, __float_as_int(x), 0x143, 0xc, 0xf, false); x += __int_as_float(t); // row_bcast:31
    return x;
}

// ---------------------------------------------------------------------------
// Phase 1 body: role-split pairwise reduction over one 3072-float chunk.
//   t < 128 : 66 dot-product accumulators (e2)
//   t >= 128: 55 L1-distance accumulators (e1)   (same d-slice; dup loads hit L1)
// Caps per-thread live values at ~110-130 VGPR so 3 blocks/CU is natural.
// ---------------------------------------------------------------------------
__device__ __forceinline__ void pair_phase(const float* __restrict__ xb, long cbase, int t,
                                           double* __restrict__ e2b, double* __restrict__ e1b) {
    __shared__ float red2[2][NP2];
    __shared__ float red1[2][NP1];
    const int wave = t >> 6, lane = t & 63;
    const int rt = t & 127;

    if (t < 128) {
        float acc[NP2];
#pragma unroll
        for (int p = 0; p < NP2; ++p) acc[p] = 0.f;
#pragma unroll 1
        for (int k = 0; k < K1; ++k) {
            const long d = cbase + (long)k * 512 + (long)rt * 4;
            float4 v[N_];
#pragma unroll
            for (int m = 0; m < N_; ++m)
                v[m] = *reinterpret_cast<const float4*>(xb + (long)m * D_ + d);
            int p = 0;
#pragma unroll
            for (int i = 0; i < N_; ++i)
#pragma unroll
                for (int j = i; j < N_; ++j, ++p)
                    acc[p] += v[i].x * v[j].x + v[i].y * v[j].y +
                              v[i].z * v[j].z + v[i].w * v[j].w;
        }
#pragma unroll
        for (int p = 0; p < NP2; ++p) {
            const float s = wave_red_add(acc[p]);
            if (lane == 63) red2[wave][p] = s;
        }
    } else {
        float acc[NP1];
#pragma unroll
        for (int p = 0; p < NP1; ++p) acc[p] = 0.f;
#pragma unroll 1
        for (int k = 0; k < K1; ++k) {
            const long d = cbase + (long)k * 512 + (long)rt * 4;
            float4 v[N_];
#pragma unroll
            for (int m = 0; m < N_; ++m)
                v[m] = *reinterpret_cast<const float4*>(xb + (long)m * D_ + d);
            int p = 0;
#pragma unroll
            for (int i = 0; i < N_; ++i)
#pragma unroll
                for (int j = i + 1; j < N_; ++j, ++p)
                    acc[p] += fabsf(v[i].x - v[j].x) + fabsf(v[i].y - v[j].y) +
                              fabsf(v[i].z - v[j].z) + fabsf(v[i].w - v[j].w);
        }
#pragma unroll
        for (int p = 0; p < NP1; ++p) {
            const float s = wave_red_add(acc[p]);
            if (lane == 63) red1[wave - 2][p] = s;
        }
    }
    __syncthreads();
    if (t < NP2)
        atomicAdd(&e2b[t], (double)(red2[0][t] + red2[1][t]));
    else if (t >= 128 && t < 128 + NP1)
        atomicAdd(&e1b[t - 128], (double)(red1[0][t - 128] + red1[1][t - 128]));
}

// ---------------------------------------------------------------------------
// Phase 2 body: E = e1*e2 (symmetric, diag 0); M = gamma*softmax(max-E) + I.
// Cheap enough to run redundantly in every block (reads 121 doubles from L2).
// ---------------------------------------------------------------------------
__device__ __forceinline__ void build_M(const double* __restrict__ e2b,
                                        const double* __restrict__ e1b,
                                        const float* __restrict__ gamma,
                                        int t, float* __restrict__ M) {
    __shared__ double E[N_][N_];
    if (t < NP2) {
        int rem = t, i = 0, cnt = N_;
        while (rem >= cnt) { rem -= cnt; --cnt; ++i; }
        const int j = i + rem;
        double e = 0.0;
        if (j > i) {
            const int q = i * (2 * N_ - 1 - i) / 2 + (j - i - 1);
            e = e1b[q] * e2b[t];
        }
        E[i][j] = e;
        E[j][i] = e;
    }
    __syncthreads();
    if (t < N_) {
        const int i = t;
        double mn = E[i][0];
#pragma unroll
        for (int j = 1; j < N_; ++j) mn = fmin(mn, E[i][j]);
        double ex[N_], s = 0.0;
#pragma unroll
        for (int j = 0; j < N_; ++j) { ex[j] = exp(mn - E[i][j]); s += ex[j]; }
        const float g = gamma[0];
        const double inv = 1.0 / s;
#pragma unroll
        for (int j = 0; j < N_; ++j)
            M[i * N_ + j] = (float)(ex[j] * inv) * g + (i == j ? 1.0f : 0.0f);
    }
}

// ---------------------------------------------------------------------------
// Phase 3 body: out[n,d] = sum_m M[n][m] * x[m,d] over this block's chunk.
// n-loop kept runtime (#pragma unroll 1) so the 121 M values stay in LDS
// instead of being hoisted into 121 registers. Stores nontemporal.
// ---------------------------------------------------------------------------
__device__ __forceinline__ void apply_phase(const float* __restrict__ xb, float* __restrict__ ob,
                                            long cbase, int t, const float* __restrict__ M) {
#pragma unroll 1
    for (int k = 0; k < K3; ++k) {
        const long d = cbase + (long)k * 1024 + (long)t * 4;
        float4 v[N_];
#pragma unroll
        for (int m = 0; m < N_; ++m)
            v[m] = *reinterpret_cast<const float4*>(xb + (long)m * D_ + d);
#pragma unroll 1
        for (int n = 0; n < N_; ++n) {
            float4 o = make_float4(0.f, 0.f, 0.f, 0.f);
#pragma unroll
            for (int m = 0; m < N_; ++m) {
                const float w = M[n * N_ + m];
                o.x += w * v[m].x; o.y += w * v[m].y;
                o.z += w * v[m].z; o.w += w * v[m].w;
            }
            union { float4 f; nfloat4 n4; } u;
            u.f = o;
            __builtin_nontemporal_store(u.n4, reinterpret_cast<nfloat4*>(ob + (long)n * D_ + d));
        }
    }
}

// ---------------------------------------------------------------------------
// Fused cooperative kernel: reduce -> grid.sync -> softmax -> apply.
// Grid (192,4) = 768 blocks = exactly 3/CU; x stays L3-hot into phase 3.
// ---------------------------------------------------------------------------
__global__ __launch_bounds__(TPB) void fused_kernel(const float* __restrict__ x,
                                                    const float* __restrict__ gamma,
                                                    double* __restrict__ e2ws,
                                                    double* __restrict__ e1ws,
                                                    float* __restrict__ out) {
    const int b = blockIdx.y, chunk = blockIdx.x, t = threadIdx.x;
    const float* xb = x + (long)b * N_ * D_;
    const long cbase = (long)chunk * CFL;

    pair_phase(xb, cbase, t, e2ws + b * NP2, e1ws + b * NP1);

    cg::this_grid().sync();

    __shared__ float M[N_ * N_];
    build_M(e2ws + b * NP2, e1ws + b * NP1, gamma, t, M);
    __syncthreads();

    apply_phase(xb, out + (long)b * N_ * D_, cbase, t, M);
}

// ---------------------------------------------------------------------------
// Fallback path (same bodies, 3 launches) if residency < 3 blocks/CU.
// ---------------------------------------------------------------------------
__global__ __launch_bounds__(TPB) void reduce_kernel(const float* __restrict__ x,
                                                     double* __restrict__ e2ws,
                                                     double* __restrict__ e1ws) {
    const int b = blockIdx.y, chunk = blockIdx.x, t = threadIdx.x;
    pair_phase(x + (long)b * N_ * D_, (long)chunk * CFL, t, e2ws + b * NP2, e1ws + b * NP1);
}

__global__ __launch_bounds__(128) void attn_kernel(const double* __restrict__ e2ws,
                                                   const double* __restrict__ e1ws,
                                                   const float* __restrict__ gamma,
                                                   float* __restrict__ Mws) {
    const int b = blockIdx.x, t = threadIdx.x;
    __shared__ float M[N_ * N_];
    build_M(e2ws + b * NP2, e1ws + b * NP1, gamma, t, M);
    __syncthreads();
    if (t < N_ * N_) Mws[b * N_ * N_ + t] = M[t];
}

__global__ __launch_bounds__(TPB) void apply_kernel(const float* __restrict__ x,
                                                    const float* __restrict__ Mws,
                                                    float* __restrict__ out) {
    const int b = blockIdx.y, chunk = blockIdx.x, t = threadIdx.x;
    __shared__ float M[N_ * N_];
    if (t < N_ * N_) M[t] = Mws[b * N_ * N_ + t];
    __syncthreads();
    apply_phase(x + (long)b * N_ * D_, out + (long)b * N_ * D_, (long)chunk * CFL, t, M);
}

// ---------------------------------------------------------------------------
extern "C" void kernel_launch(void* const* d_in, const int* in_sizes, int n_in,
                              void* d_out, int out_size, void* d_ws, size_t ws_size,
                              hipStream_t stream) {
    const float* x     = (const float*)d_in[0];
    const float* gamma = (const float*)d_in[1];
    float* out         = (float*)d_out;

    double* e2ws = (double*)d_ws;                // B_*NP2 doubles
    double* e1ws = e2ws + B_ * NP2;              // B_*NP1 doubles
    float*  Mws  = (float*)(e1ws + B_ * NP1);    // B_*121 floats (fallback only)

    // zero fp64 accumulators (ws is poisoned before every launch)
    hipMemsetAsync(d_ws, 0, (size_t)(B_ * (NP2 + NP1)) * sizeof(double), stream);

    static int coop = -1;
    if (coop < 0) {
        int nb = 0;
        if (hipOccupancyMaxActiveBlocksPerMultiprocessor(&nb, fused_kernel, TPB, 0) != hipSuccess)
            nb = 0;
        coop = (nb >= 3) ? 1 : 0;   // need all 768 blocks co-resident (3/CU)
    }

    dim3 grid(CHUNKS, B_);
    if (coop) {
        void* args[] = {(void*)&x, (void*)&gamma, (void*)&e2ws, (void*)&e1ws, (void*)&out};
        hipLaunchCooperativeKernel((void*)fused_kernel, grid, dim3(TPB), args, 0, stream);
    } else {
        reduce_kernel<<<grid, TPB, 0, stream>>>(x, e2ws, e1ws);
        attn_kernel<<<B_, 128, 0, stream>>>(e2ws, e1ws, gamma, Mws);
        apply_kernel<<<grid, TPB, 0, stream>>>(x, Mws, out);
    }
}